// Round 5
// baseline (361.426 us; speedup 1.0000x reference)
//
#include <hip/hip_runtime.h>

// ACE symmetrizer, fused: b[r,f,n] = sum_m cg[r,m] * A[f,m,n] for 5 (A, CG0, CG1)
// groups in ONE kernel. Memory-bound: 499MB read + 537MB write -> ~165us floor.
//
// Round-5 changes vs round-4 (218us, ~4.9 TB/s eff):
//  - 512-thread blocks, r-split: tid<256 -> r0..15, tid>=256 -> r16..31.
//    acc[16] (64 VGPR) instead of acc[32] (128) -> ~100 VGPR -> 4 waves/SIMD
//    (16 waves/CU, was 12): more independent streams through R/W turnarounds.
//  - A loads now CACHED (sibling half re-reads same rows -> L1/L2 hit, HBM
//    fetch unchanged); stores stay nontemporal (keep write stream out of L2).
//  - each half s_loads only its 16 coefs -> 1x s_load_dwordx16 per m.

typedef float f32x4 __attribute__((ext_vector_type(4)));

#define NN 1024

// output float offsets (return order: b0 x5 then b1 x5)
#define O0_0 0UL
#define O0_1 8388608UL
#define O0_2 16777216UL
#define O0_3 25165824UL
#define O0_4 29360128UL
#define O1_0 33554432UL
#define O1_1 58720256UL
#define O1_2 83886080UL
#define O1_3 109051904UL
#define O1_4 121634816UL

// padded cgT float offsets in ws: 32*MP per op, MP = {12,28,52,28,48}
#define WP_0 0
#define WP_1 384
#define WP_2 1280
#define WP_3 2944
#define WP_4 3840
#define WP_TOT 5376

__global__ __launch_bounds__(256)
void cg_transpose(const float* __restrict__ c00, const float* __restrict__ c01,
                  const float* __restrict__ c02, const float* __restrict__ c03,
                  const float* __restrict__ c04,
                  const float* __restrict__ c10, const float* __restrict__ c11,
                  const float* __restrict__ c12, const float* __restrict__ c13,
                  const float* __restrict__ c14,
                  float* __restrict__ w)
{
    int t = blockIdx.x * 256 + threadIdx.x;
    if (t >= WP_TOT) return;
    int M, off; const float* g0; const float* g1;
    if      (t < WP_1) { M = 9;  off = WP_0; g0 = c00; g1 = c10; }
    else if (t < WP_2) { M = 25; off = WP_1; g0 = c01; g1 = c11; }
    else if (t < WP_3) { M = 49; off = WP_2; g0 = c02; g1 = c12; }
    else if (t < WP_4) { M = 27; off = WP_3; g0 = c03; g1 = c13; }
    else               { M = 45; off = WP_4; g0 = c04; g1 = c14; }
    int loc = t - off;
    int m = loc >> 5, r = loc & 31;
    float v = 0.f;
    if (m < M) v = (r < 8) ? g0[r * M + m] : g1[(r - 8) * M + m];
    w[t] = v;
}

// One (op, f) pair, one r-half (16 rows). cgh = cgT row base for this half
// (cgT + WP_op + half*16); Af = A + f*M*NN + n0.
template<int M, int MP>
__device__ __forceinline__ void run_op(const float* __restrict__ Af,
                                       const float* __restrict__ cgh,
                                       float* __restrict__ p0,
                                       float* __restrict__ p1,
                                       size_t stride, int half)
{
    const f32x4* ap = reinterpret_cast<const f32x4*>(Af);

    f32x4 buf[4];
#pragma unroll
    for (int i = 0; i < 4; ++i)
        buf[i] = ap[(size_t)i * (NN / 4)];          // cached: sibling half reuses

    f32x4 acc[16];
#pragma unroll
    for (int r = 0; r < 16; ++r) acc[r] = (f32x4)(0.f);

#pragma unroll 1
    for (int m = 0; m < MP; m += 4) {
#pragma unroll
        for (int i = 0; i < 4; ++i) {
            const f32x4 cur = buf[i];
            int nm = m + 4 + i;
            nm = (nm < M) ? nm : (M - 1);           // clamped prefetch (cache hit)
            buf[i] = ap[(size_t)nm * (NN / 4)];
            const float* c = cgh + (size_t)(m + i) * 32;  // uniform -> s_load_dwordx16
#pragma unroll
            for (int r = 0; r < 16; ++r) {
                const float cr = c[r];
                acc[r].x = fmaf(cr, cur.x, acc[r].x);
                acc[r].y = fmaf(cr, cur.y, acc[r].y);
                acc[r].z = fmaf(cr, cur.z, acc[r].z);
                acc[r].w = fmaf(cr, cur.w, acc[r].w);
            }
        }
    }

    if (half == 0) {
        // global r = 0..15: rows 0..7 -> out0, rows 8..15 -> out1 rows 0..7
#pragma unroll
        for (int r = 0; r < 8; ++r)
            __builtin_nontemporal_store(acc[r], reinterpret_cast<f32x4*>(p0 + (size_t)r * stride));
#pragma unroll
        for (int r = 0; r < 8; ++r)
            __builtin_nontemporal_store(acc[8 + r], reinterpret_cast<f32x4*>(p1 + (size_t)r * stride));
    } else {
        // global r = 16..31 -> out1 rows 8..23
#pragma unroll
        for (int r = 0; r < 16; ++r)
            __builtin_nontemporal_store(acc[r], reinterpret_cast<f32x4*>(p1 + (size_t)(8 + r) * stride));
    }
}

__global__ __launch_bounds__(512, 4)
void ace_sym_all(const float* __restrict__ A0, const float* __restrict__ A1,
                 const float* __restrict__ A2, const float* __restrict__ A3,
                 const float* __restrict__ A4,
                 const float* __restrict__ cgT, float* __restrict__ out)
{
    const int bid = blockIdx.x;
    const int tid = (int)threadIdx.x;
    const int half = tid >> 8;                 // wave-uniform (4-wave boundary)
    const int n0 = (tid & 255) * 4;

    // heavy-first: M=49 (F=1024), M=45 (512), M=25 (1024), M=27 (512), M=9 (1024)
    if (bid < 1024) {
        const size_t f = bid;
        run_op<49, 52>(A2 + f * 49 * NN + n0, cgT + WP_2 + half * 16,
                       out + O0_2 + f * NN + n0, out + O1_2 + f * NN + n0,
                       (size_t)1024 * NN, half);
    } else if (bid < 1536) {
        const size_t f = bid - 1024;
        run_op<45, 48>(A4 + f * 45 * NN + n0, cgT + WP_4 + half * 16,
                       out + O0_4 + f * NN + n0, out + O1_4 + f * NN + n0,
                       (size_t)512 * NN, half);
    } else if (bid < 2560) {
        const size_t f = bid - 1536;
        run_op<25, 28>(A1 + f * 25 * NN + n0, cgT + WP_1 + half * 16,
                       out + O0_1 + f * NN + n0, out + O1_1 + f * NN + n0,
                       (size_t)1024 * NN, half);
    } else if (bid < 3072) {
        const size_t f = bid - 2560;
        run_op<27, 28>(A3 + f * 27 * NN + n0, cgT + WP_3 + half * 16,
                       out + O0_3 + f * NN + n0, out + O1_3 + f * NN + n0,
                       (size_t)512 * NN, half);
    } else {
        const size_t f = bid - 3072;
        run_op<9, 12>(A0 + f * 9 * NN + n0, cgT + WP_0 + half * 16,
                      out + O0_0 + f * NN + n0, out + O1_0 + f * NN + n0,
                      (size_t)1024 * NN, half);
    }
}

extern "C" void kernel_launch(void* const* d_in, const int* in_sizes, int n_in,
                              void* d_out, int out_size, void* d_ws, size_t ws_size,
                              hipStream_t stream)
{
    const float* A0 = (const float*)d_in[0];
    const float* A1 = (const float*)d_in[1];
    const float* A2 = (const float*)d_in[2];
    const float* A3 = (const float*)d_in[3];
    const float* A4 = (const float*)d_in[4];

    float* wsT = (float*)d_ws;

    hipLaunchKernelGGL(cg_transpose, dim3((WP_TOT + 255) / 256), dim3(256), 0, stream,
                       (const float*)d_in[5], (const float*)d_in[6], (const float*)d_in[7],
                       (const float*)d_in[8], (const float*)d_in[9],
                       (const float*)d_in[10], (const float*)d_in[11], (const float*)d_in[12],
                       (const float*)d_in[13], (const float*)d_in[14], wsT);

    hipLaunchKernelGGL(ace_sym_all, dim3(4096), dim3(512), 0, stream,
                       A0, A1, A2, A3, A4, (const float*)wsT, (float*)d_out);
}

// Round 6
// 225.232 us; speedup vs baseline: 1.6047x; 1.6047x over previous
//
#include <hip/hip_runtime.h>

// ACE symmetrizer, fused: b[r,f,n] = sum_m cg[r,m] * A[f,m,n] for 5 (A, CG0, CG1)
// groups in ONE kernel. Memory-bound: ~500MB read + 537MB write.
//
// Round-6: EXACT round-4 structure (218us) with ONE change:
//  - A loads are CACHED (plain) instead of nontemporal. Round-5's counters
//    showed FETCH_SIZE=287MB with cached loads (L3 absorbs ~200MB of A across
//    graph replays); nt loads bypass L3 and pay the full 499MB from HBM.
//  - stores remain nontemporal: outputs are never re-read, and keeping the
//    537MB write stream out of L2/L3 preserves cache capacity for A.
//  - NO launch_bounds min-waves arg (round-5 lesson: forcing 4 waves/EU capped
//    VGPR at 64 -> scratch spills -> +133MB write traffic, 361us).

typedef float f32x4 __attribute__((ext_vector_type(4)));

#define NN 1024

// output float offsets (return order: b0 x5 then b1 x5)
#define O0_0 0UL
#define O0_1 8388608UL
#define O0_2 16777216UL
#define O0_3 25165824UL
#define O0_4 29360128UL
#define O1_0 33554432UL
#define O1_1 58720256UL
#define O1_2 83886080UL
#define O1_3 109051904UL
#define O1_4 121634816UL

// padded cgT float offsets in ws: 32*MP per op, MP = {12,28,52,28,48}
#define WP_0 0
#define WP_1 384
#define WP_2 1280
#define WP_3 2944
#define WP_4 3840
#define WP_TOT 5376

__global__ __launch_bounds__(256)
void cg_transpose(const float* __restrict__ c00, const float* __restrict__ c01,
                  const float* __restrict__ c02, const float* __restrict__ c03,
                  const float* __restrict__ c04,
                  const float* __restrict__ c10, const float* __restrict__ c11,
                  const float* __restrict__ c12, const float* __restrict__ c13,
                  const float* __restrict__ c14,
                  float* __restrict__ w)
{
    int t = blockIdx.x * 256 + threadIdx.x;
    if (t >= WP_TOT) return;
    int M, off; const float* g0; const float* g1;
    if      (t < WP_1) { M = 9;  off = WP_0; g0 = c00; g1 = c10; }
    else if (t < WP_2) { M = 25; off = WP_1; g0 = c01; g1 = c11; }
    else if (t < WP_3) { M = 49; off = WP_2; g0 = c02; g1 = c12; }
    else if (t < WP_4) { M = 27; off = WP_3; g0 = c03; g1 = c13; }
    else               { M = 45; off = WP_4; g0 = c04; g1 = c14; }
    int loc = t - off;
    int m = loc >> 5, r = loc & 31;
    float v = 0.f;
    if (m < M) v = (r < 8) ? g0[r * M + m] : g1[(r - 8) * M + m];
    w[t] = v;
}

template<int M, int MP>
__device__ __forceinline__ void run_op(const float* __restrict__ Af,  // A + f*M*NN + n0
                                       const float* __restrict__ cg,  // cgT + WP_op, [MP][32]
                                       float* __restrict__ p0,        // out + o0 + f*NN + n0
                                       float* __restrict__ p1,        // out + o1 + f*NN + n0
                                       size_t stride)                 // F*NN
{
    const f32x4* ap = reinterpret_cast<const f32x4*>(Af);

    f32x4 buf[4];
#pragma unroll
    for (int i = 0; i < 4; ++i) {
        const int mi = (i < M) ? i : (M - 1);
        buf[i] = ap[(size_t)mi * (NN / 4)];          // cached: L3 reuse across replays
    }

    f32x4 acc[32];
#pragma unroll
    for (int r = 0; r < 32; ++r) acc[r] = (f32x4)(0.f);

#pragma unroll 1
    for (int m = 0; m < MP; m += 4) {
#pragma unroll
        for (int i = 0; i < 4; ++i) {
            const f32x4 cur = buf[i];
            int nm = m + 4 + i;
            nm = (nm < M) ? nm : (M - 1);            // clamped prefetch (cache hit)
            buf[i] = ap[(size_t)nm * (NN / 4)];
            const float* c = cg + (size_t)(m + i) * 32;   // uniform -> s_load x2
#pragma unroll
            for (int r = 0; r < 32; ++r) {
                const float cr = c[r];
                acc[r].x = fmaf(cr, cur.x, acc[r].x);
                acc[r].y = fmaf(cr, cur.y, acc[r].y);
                acc[r].z = fmaf(cr, cur.z, acc[r].z);
                acc[r].w = fmaf(cr, cur.w, acc[r].w);
            }
        }
    }

#pragma unroll
    for (int r = 0; r < 8; ++r)
        __builtin_nontemporal_store(acc[r], reinterpret_cast<f32x4*>(p0 + r * stride));
#pragma unroll
    for (int r = 0; r < 24; ++r)
        __builtin_nontemporal_store(acc[8 + r], reinterpret_cast<f32x4*>(p1 + r * stride));
}

__global__ __launch_bounds__(256)
void ace_sym_all(const float* __restrict__ A0, const float* __restrict__ A1,
                 const float* __restrict__ A2, const float* __restrict__ A3,
                 const float* __restrict__ A4,
                 const float* __restrict__ cgT, float* __restrict__ out)
{
    const int bid = blockIdx.x;
    const int n0 = (int)threadIdx.x * 4;

    // heavy-first: M=49 (F=1024), M=45 (512), M=25 (1024), M=27 (512), M=9 (1024)
    if (bid < 1024) {
        const size_t f = bid;
        run_op<49, 52>(A2 + f * 49 * NN + n0, cgT + WP_2,
                       out + O0_2 + f * NN + n0, out + O1_2 + f * NN + n0,
                       (size_t)1024 * NN);
    } else if (bid < 1536) {
        const size_t f = bid - 1024;
        run_op<45, 48>(A4 + f * 45 * NN + n0, cgT + WP_4,
                       out + O0_4 + f * NN + n0, out + O1_4 + f * NN + n0,
                       (size_t)512 * NN);
    } else if (bid < 2560) {
        const size_t f = bid - 1536;
        run_op<25, 28>(A1 + f * 25 * NN + n0, cgT + WP_1,
                       out + O0_1 + f * NN + n0, out + O1_1 + f * NN + n0,
                       (size_t)1024 * NN);
    } else if (bid < 3072) {
        const size_t f = bid - 2560;
        run_op<27, 28>(A3 + f * 27 * NN + n0, cgT + WP_3,
                       out + O0_3 + f * NN + n0, out + O1_3 + f * NN + n0,
                       (size_t)512 * NN);
    } else {
        const size_t f = bid - 3072;
        run_op<9, 12>(A0 + f * 9 * NN + n0, cgT + WP_0,
                      out + O0_0 + f * NN + n0, out + O1_0 + f * NN + n0,
                      (size_t)1024 * NN);
    }
}

extern "C" void kernel_launch(void* const* d_in, const int* in_sizes, int n_in,
                              void* d_out, int out_size, void* d_ws, size_t ws_size,
                              hipStream_t stream)
{
    const float* A0 = (const float*)d_in[0];
    const float* A1 = (const float*)d_in[1];
    const float* A2 = (const float*)d_in[2];
    const float* A3 = (const float*)d_in[3];
    const float* A4 = (const float*)d_in[4];

    float* wsT = (float*)d_ws;

    hipLaunchKernelGGL(cg_transpose, dim3((WP_TOT + 255) / 256), dim3(256), 0, stream,
                       (const float*)d_in[5], (const float*)d_in[6], (const float*)d_in[7],
                       (const float*)d_in[8], (const float*)d_in[9],
                       (const float*)d_in[10], (const float*)d_in[11], (const float*)d_in[12],
                       (const float*)d_in[13], (const float*)d_in[14], wsT);

    hipLaunchKernelGGL(ace_sym_all, dim3(4096), dim3(256), 0, stream,
                       A0, A1, A2, A3, A4, (const float*)wsT, (float*)d_out);
}

// Round 7
// 207.253 us; speedup vs baseline: 1.7439x; 1.0867x over previous
//
#include <hip/hip_runtime.h>

// ACE symmetrizer, fused: b[r,f,n] = sum_m cg[r,m] * A[f,m,n] for 5 (A, CG0, CG1)
// groups in ONE kernel. Memory-bound: ~500MB read + 537MB write -> ~165us floor.
//
// Round-7 vs round-4 (218us): float2 per thread instead of float4.
//  - acc[32] x f32x2 = 64 VGPR (+buf/addr ~ 95 total) -> 4 waves/SIMD
//    (was ~170 VGPR -> 2 waves/SIMD). 2x wave parallelism for latency hiding
//    and R/W stream mixing; no spills (no forced launch-bounds cap).
//  - 8192 blocks of 256 thr; block = (op, f, n-half of 512). No duplicate A
//    reads (each thread keeps all 32 r-rows). 8B/lane loads (sweet spot).
//  - nt loads + nt stores (round-4 config; round-6 showed cached ~= nt).

typedef float f32x2 __attribute__((ext_vector_type(2)));

#define NN 1024

// output float offsets (return order: b0 x5 then b1 x5)
#define O0_0 0UL
#define O0_1 8388608UL
#define O0_2 16777216UL
#define O0_3 25165824UL
#define O0_4 29360128UL
#define O1_0 33554432UL
#define O1_1 58720256UL
#define O1_2 83886080UL
#define O1_3 109051904UL
#define O1_4 121634816UL

// padded cgT float offsets in ws: 32*MP per op, MP = {12,28,52,28,48}
#define WP_0 0
#define WP_1 384
#define WP_2 1280
#define WP_3 2944
#define WP_4 3840
#define WP_TOT 5376

__global__ __launch_bounds__(256)
void cg_transpose(const float* __restrict__ c00, const float* __restrict__ c01,
                  const float* __restrict__ c02, const float* __restrict__ c03,
                  const float* __restrict__ c04,
                  const float* __restrict__ c10, const float* __restrict__ c11,
                  const float* __restrict__ c12, const float* __restrict__ c13,
                  const float* __restrict__ c14,
                  float* __restrict__ w)
{
    int t = blockIdx.x * 256 + threadIdx.x;
    if (t >= WP_TOT) return;
    int M, off; const float* g0; const float* g1;
    if      (t < WP_1) { M = 9;  off = WP_0; g0 = c00; g1 = c10; }
    else if (t < WP_2) { M = 25; off = WP_1; g0 = c01; g1 = c11; }
    else if (t < WP_3) { M = 49; off = WP_2; g0 = c02; g1 = c12; }
    else if (t < WP_4) { M = 27; off = WP_3; g0 = c03; g1 = c13; }
    else               { M = 45; off = WP_4; g0 = c04; g1 = c14; }
    int loc = t - off;
    int m = loc >> 5, r = loc & 31;
    float v = 0.f;
    if (m < M) v = (r < 8) ? g0[r * M + m] : g1[(r - 8) * M + m];
    w[t] = v;
}

template<int M, int MP>
__device__ __forceinline__ void run_op(const float* __restrict__ Af,  // A + f*M*NN + n0
                                       const float* __restrict__ cg,  // cgT + WP_op, [MP][32]
                                       float* __restrict__ p0,        // out + o0 + f*NN + n0
                                       float* __restrict__ p1,        // out + o1 + f*NN + n0
                                       size_t stride)                 // F*NN
{
    const f32x2* ap = reinterpret_cast<const f32x2*>(Af);

    f32x2 buf[4];
#pragma unroll
    for (int i = 0; i < 4; ++i) {
        const int mi = (i < M) ? i : (M - 1);
        buf[i] = __builtin_nontemporal_load(ap + (size_t)mi * (NN / 2));
    }

    f32x2 acc[32];
#pragma unroll
    for (int r = 0; r < 32; ++r) acc[r] = (f32x2)(0.f);

#pragma unroll 1
    for (int m = 0; m < MP; m += 4) {
#pragma unroll
        for (int i = 0; i < 4; ++i) {
            const f32x2 cur = buf[i];
            int nm = m + 4 + i;
            nm = (nm < M) ? nm : (M - 1);            // clamped prefetch
            buf[i] = __builtin_nontemporal_load(ap + (size_t)nm * (NN / 2));
            const float* c = cg + (size_t)(m + i) * 32;   // uniform -> s_load x2
#pragma unroll
            for (int r = 0; r < 32; ++r) {
                const float cr = c[r];
                acc[r].x = fmaf(cr, cur.x, acc[r].x);
                acc[r].y = fmaf(cr, cur.y, acc[r].y);
            }
        }
    }

#pragma unroll
    for (int r = 0; r < 8; ++r)
        __builtin_nontemporal_store(acc[r], reinterpret_cast<f32x2*>(p0 + r * stride));
#pragma unroll
    for (int r = 0; r < 24; ++r)
        __builtin_nontemporal_store(acc[8 + r], reinterpret_cast<f32x2*>(p1 + r * stride));
}

__global__ __launch_bounds__(256)
void ace_sym_all(const float* __restrict__ A0, const float* __restrict__ A1,
                 const float* __restrict__ A2, const float* __restrict__ A3,
                 const float* __restrict__ A4,
                 const float* __restrict__ cgT, float* __restrict__ out)
{
    const int bid = blockIdx.x;
    // block covers 512 n: half = bid&1 selects n in [0,512) or [512,1024)
    const int n0base = (int)threadIdx.x * 2;

    // heavy-first: M=49 (F=1024), M=45 (512), M=25 (1024), M=27 (512), M=9 (1024)
    if (bid < 2048) {
        const size_t f = bid >> 1;
        const int n0 = ((bid & 1) << 9) + n0base;
        run_op<49, 52>(A2 + f * 49 * NN + n0, cgT + WP_2,
                       out + O0_2 + f * NN + n0, out + O1_2 + f * NN + n0,
                       (size_t)1024 * NN);
    } else if (bid < 3072) {
        const int loc = bid - 2048;
        const size_t f = loc >> 1;
        const int n0 = ((loc & 1) << 9) + n0base;
        run_op<45, 48>(A4 + f * 45 * NN + n0, cgT + WP_4,
                       out + O0_4 + f * NN + n0, out + O1_4 + f * NN + n0,
                       (size_t)512 * NN);
    } else if (bid < 5120) {
        const int loc = bid - 3072;
        const size_t f = loc >> 1;
        const int n0 = ((loc & 1) << 9) + n0base;
        run_op<25, 28>(A1 + f * 25 * NN + n0, cgT + WP_1,
                       out + O0_1 + f * NN + n0, out + O1_1 + f * NN + n0,
                       (size_t)1024 * NN);
    } else if (bid < 6144) {
        const int loc = bid - 5120;
        const size_t f = loc >> 1;
        const int n0 = ((loc & 1) << 9) + n0base;
        run_op<27, 28>(A3 + f * 27 * NN + n0, cgT + WP_3,
                       out + O0_3 + f * NN + n0, out + O1_3 + f * NN + n0,
                       (size_t)512 * NN);
    } else {
        const int loc = bid - 6144;
        const size_t f = loc >> 1;
        const int n0 = ((loc & 1) << 9) + n0base;
        run_op<9, 12>(A0 + f * 9 * NN + n0, cgT + WP_0,
                      out + O0_0 + f * NN + n0, out + O1_0 + f * NN + n0,
                      (size_t)1024 * NN);
    }
}

extern "C" void kernel_launch(void* const* d_in, const int* in_sizes, int n_in,
                              void* d_out, int out_size, void* d_ws, size_t ws_size,
                              hipStream_t stream)
{
    const float* A0 = (const float*)d_in[0];
    const float* A1 = (const float*)d_in[1];
    const float* A2 = (const float*)d_in[2];
    const float* A3 = (const float*)d_in[3];
    const float* A4 = (const float*)d_in[4];

    float* wsT = (float*)d_ws;

    hipLaunchKernelGGL(cg_transpose, dim3((WP_TOT + 255) / 256), dim3(256), 0, stream,
                       (const float*)d_in[5], (const float*)d_in[6], (const float*)d_in[7],
                       (const float*)d_in[8], (const float*)d_in[9],
                       (const float*)d_in[10], (const float*)d_in[11], (const float*)d_in[12],
                       (const float*)d_in[13], (const float*)d_in[14], wsT);

    hipLaunchKernelGGL(ace_sym_all, dim3(8192), dim3(256), 0, stream,
                       A0, A1, A2, A3, A4, (const float*)wsT, (float*)d_out);
}